// Round 1
// baseline (247.695 us; speedup 1.0000x reference)
//
#include <hip/hip_runtime.h>
#include <math.h>

// Problem constants (from reference): x is [B=256, C=64, N=2048] fp32.
// Reference collapses to: out[b,c,n] = softmax_n(max_c x[b,c,n]) * x[b,c,n]
// (SVD full reconstruction of a Hankel matrix + anti-diagonal averaging is
//  the identity on xm).

#define B_DIM 256
#define C_DIM 64
#define N_DIM 2048
#define THREADS 512   // each thread owns 4 consecutive n's (float4)

__global__ __launch_bounds__(THREADS)
void ssa_gate_kernel(const float* __restrict__ x, float* __restrict__ out) {
    const int b = blockIdx.x;
    const int t = threadIdx.x;
    const int lane = t & 63;
    const int wid  = t >> 6;          // 8 waves of 64

    const size_t base = (size_t)b * (C_DIM * N_DIM);
    const float4* __restrict__ xb = (const float4*)(x + base);
    float4* __restrict__ ob = (float4*)(out + base);
    const int stride4 = N_DIM / 4;    // 512 float4 per channel row

    __shared__ float sred[8];

    // ---- Pass 1: xm[n] = max over c, per-thread over its 4 n's ----
    float4 m;
    m.x = -INFINITY; m.y = -INFINITY; m.z = -INFINITY; m.w = -INFINITY;
    #pragma unroll 8
    for (int c = 0; c < C_DIM; ++c) {
        float4 v = xb[c * stride4 + t];
        m.x = fmaxf(m.x, v.x);
        m.y = fmaxf(m.y, v.y);
        m.z = fmaxf(m.z, v.z);
        m.w = fmaxf(m.w, v.w);
    }

    // ---- Block-wide max (softmax stabilizer) ----
    float tm = fmaxf(fmaxf(m.x, m.y), fmaxf(m.z, m.w));
    #pragma unroll
    for (int off = 32; off > 0; off >>= 1)
        tm = fmaxf(tm, __shfl_down(tm, off, 64));
    if (lane == 0) sred[wid] = tm;
    __syncthreads();
    float M = sred[0];
    #pragma unroll
    for (int i = 1; i < 8; ++i) M = fmaxf(M, sred[i]);
    __syncthreads();  // sred reused below

    // ---- exp and block-wide sum ----
    float4 e;
    e.x = __expf(m.x - M);
    e.y = __expf(m.y - M);
    e.z = __expf(m.z - M);
    e.w = __expf(m.w - M);
    float ts = (e.x + e.y) + (e.z + e.w);
    #pragma unroll
    for (int off = 32; off > 0; off >>= 1)
        ts += __shfl_down(ts, off, 64);
    if (lane == 0) sred[wid] = ts;
    __syncthreads();
    float S = 0.0f;
    #pragma unroll
    for (int i = 0; i < 8; ++i) S += sred[i];

    const float inv = 1.0f / S;
    float4 g;
    g.x = e.x * inv; g.y = e.y * inv; g.z = e.z * inv; g.w = e.w * inv;

    // ---- Pass 2: out = gate * x (gate stays in registers; same n's) ----
    #pragma unroll 8
    for (int c = 0; c < C_DIM; ++c) {
        float4 v = xb[c * stride4 + t];
        float4 o;
        o.x = v.x * g.x;
        o.y = v.y * g.y;
        o.z = v.z * g.z;
        o.w = v.w * g.w;
        ob[c * stride4 + t] = o;
    }
}

extern "C" void kernel_launch(void* const* d_in, const int* in_sizes, int n_in,
                              void* d_out, int out_size, void* d_ws, size_t ws_size,
                              hipStream_t stream) {
    const float* x = (const float*)d_in[0];
    float* out = (float*)d_out;
    ssa_gate_kernel<<<B_DIM, THREADS, 0, stream>>>(x, out);
}

// Round 2
// 246.083 us; speedup vs baseline: 1.0066x; 1.0066x over previous
//
#include <hip/hip_runtime.h>
#include <math.h>

// out[b,c,n] = softmax_n(max_c x[b,c,n]) * x[b,c,n]   (x: [256,64,2048] fp32)
// R1: 512 thr/block -> 19% occupancy, 2.9 TB/s (latency-bound).
// R2: 1024 thr/block, channel loop split across 2 thread-groups; partial
//     maxes combined via LDS; gate broadcast via LDS. 16 waves/CU.

#define B_DIM 256
#define C_DIM 64
#define N_DIM 2048
#define COLS4 (N_DIM / 4)     // 512 float4 columns
#define THREADS 1024

__global__ __launch_bounds__(THREADS)
void ssa_gate_kernel(const float* __restrict__ x, float* __restrict__ out) {
    const int b    = blockIdx.x;
    const int t    = threadIdx.x;
    const int col  = t & (COLS4 - 1);   // 0..511 float4 column
    const int grp  = t >> 9;            // 0 or 1: which half of channels
    const int lane = t & 63;
    const int wid  = t >> 6;            // 0..15

    const size_t base = (size_t)b * (C_DIM * N_DIM);
    const float4* __restrict__ xb = (const float4*)(x + base);
    float4* __restrict__ ob = (float4*)(out + base);

    __shared__ float4 pm[2][COLS4];     // 16 KB: per-group partial max / gate
    __shared__ float  sred[16];

    const int c0 = grp * 32;

    // ---- Pass 1: partial max over this group's 32 channels ----
    float4 m;
    m.x = -INFINITY; m.y = -INFINITY; m.z = -INFINITY; m.w = -INFINITY;
    #pragma unroll 8
    for (int c = 0; c < 32; ++c) {
        float4 v = xb[(size_t)(c0 + c) * COLS4 + col];
        m.x = fmaxf(m.x, v.x);
        m.y = fmaxf(m.y, v.y);
        m.z = fmaxf(m.z, v.z);
        m.w = fmaxf(m.w, v.w);
    }
    pm[grp][col] = m;
    __syncthreads();

    // ---- Softmax over the 512 combined columns (threads 0..511 active) ----
    float4 e;                            // holds xm, then exp(xm - M)
    if (t < COLS4) {
        float4 a = pm[0][t];
        float4 c2 = pm[1][t];
        e.x = fmaxf(a.x, c2.x);
        e.y = fmaxf(a.y, c2.y);
        e.z = fmaxf(a.z, c2.z);
        e.w = fmaxf(a.w, c2.w);
        float tm = fmaxf(fmaxf(e.x, e.y), fmaxf(e.z, e.w));
        #pragma unroll
        for (int off = 32; off > 0; off >>= 1)
            tm = fmaxf(tm, __shfl_down(tm, off, 64));
        if (lane == 0) sred[wid] = tm;   // wid 0..7
    }
    __syncthreads();
    float M = sred[0];
    #pragma unroll
    for (int i = 1; i < 8; ++i) M = fmaxf(M, sred[i]);

    if (t < COLS4) {
        e.x = __expf(e.x - M);
        e.y = __expf(e.y - M);
        e.z = __expf(e.z - M);
        e.w = __expf(e.w - M);
        float ts = (e.x + e.y) + (e.z + e.w);
        #pragma unroll
        for (int off = 32; off > 0; off >>= 1)
            ts += __shfl_down(ts, off, 64);
        if (lane == 0) sred[8 + wid] = ts;  // slots 8..15
    }
    __syncthreads();
    float S = 0.0f;
    #pragma unroll
    for (int i = 8; i < 16; ++i) S += sred[i];

    if (t < COLS4) {
        const float inv = 1.0f / S;
        float4 gg;
        gg.x = e.x * inv; gg.y = e.y * inv; gg.z = e.z * inv; gg.w = e.w * inv;
        pm[0][t] = gg;                   // gate broadcast buffer
    }
    __syncthreads();

    const float4 g = pm[0][col];

    // ---- Pass 2: out = gate * x over this group's 32 channels ----
    #pragma unroll 8
    for (int c = 0; c < 32; ++c) {
        const size_t idx = (size_t)(c0 + c) * COLS4 + col;
        float4 v = xb[idx];
        float4 o;
        o.x = v.x * g.x;
        o.y = v.y * g.y;
        o.z = v.z * g.z;
        o.w = v.w * g.w;
        ob[idx] = o;
    }
}

extern "C" void kernel_launch(void* const* d_in, const int* in_sizes, int n_in,
                              void* d_out, int out_size, void* d_ws, size_t ws_size,
                              hipStream_t stream) {
    const float* x = (const float*)d_in[0];
    float* out = (float*)d_out;
    ssa_gate_kernel<<<B_DIM, THREADS, 0, stream>>>(x, out);
}

// Round 3
// 245.696 us; speedup vs baseline: 1.0081x; 1.0016x over previous
//
#include <hip/hip_runtime.h>
#include <math.h>

// out[b,c,n] = softmax_n(max_c x[b,c,n]) * x[b,c,n]   (x: [256,64,2048] fp32)
// R1: 512 thr -> 19% occ, 2.9 TB/s.  R2: 1024 thr -> 38% occ, STILL 2.9 TB/s
//   => not latency/occupancy-bound. Theory: HBM channel camping — all 256
//   blocks at identical loop phase on 512KB-strided regions hit the same
//   channel subset. R3: per-block rotation of the row loop ((c+b)&31) so the
//   instantaneous address footprint spans the whole batch stride.

#define B_DIM 256
#define C_DIM 64
#define N_DIM 2048
#define COLS4 (N_DIM / 4)     // 512 float4 columns
#define THREADS 1024

__global__ __launch_bounds__(THREADS)
void ssa_gate_kernel(const float* __restrict__ x, float* __restrict__ out) {
    const int b    = blockIdx.x;
    const int t    = threadIdx.x;
    const int col  = t & (COLS4 - 1);   // 0..511 float4 column
    const int grp  = t >> 9;            // 0 or 1: which half of channels
    const int lane = t & 63;
    const int wid  = t >> 6;            // 0..15

    const size_t base = (size_t)b * (C_DIM * N_DIM);
    const float4* __restrict__ xb = (const float4*)(x + base);
    float4* __restrict__ ob = (float4*)(out + base);

    __shared__ float4 pm[2][COLS4];     // 16 KB: per-group partial max / gate
    __shared__ float  sred[16];

    const int c0 = grp * 32;

    // ---- Pass 1: partial max over this group's 32 channels (rotated) ----
    float4 m;
    m.x = -INFINITY; m.y = -INFINITY; m.z = -INFINITY; m.w = -INFINITY;
    #pragma unroll 8
    for (int c = 0; c < 32; ++c) {
        const int cc = c0 + ((c + b) & 31);       // per-block phase rotation
        float4 v = xb[(size_t)cc * COLS4 + col];
        m.x = fmaxf(m.x, v.x);
        m.y = fmaxf(m.y, v.y);
        m.z = fmaxf(m.z, v.z);
        m.w = fmaxf(m.w, v.w);
    }
    pm[grp][col] = m;
    __syncthreads();

    // ---- Softmax over the 512 combined columns (threads 0..511 active) ----
    float4 e;                            // holds xm, then exp(xm - M)
    if (t < COLS4) {
        float4 a = pm[0][t];
        float4 c2 = pm[1][t];
        e.x = fmaxf(a.x, c2.x);
        e.y = fmaxf(a.y, c2.y);
        e.z = fmaxf(a.z, c2.z);
        e.w = fmaxf(a.w, c2.w);
        float tm = fmaxf(fmaxf(e.x, e.y), fmaxf(e.z, e.w));
        #pragma unroll
        for (int off = 32; off > 0; off >>= 1)
            tm = fmaxf(tm, __shfl_down(tm, off, 64));
        if (lane == 0) sred[wid] = tm;   // wid 0..7
    }
    __syncthreads();
    float M = sred[0];
    #pragma unroll
    for (int i = 1; i < 8; ++i) M = fmaxf(M, sred[i]);

    if (t < COLS4) {
        e.x = __expf(e.x - M);
        e.y = __expf(e.y - M);
        e.z = __expf(e.z - M);
        e.w = __expf(e.w - M);
        float ts = (e.x + e.y) + (e.z + e.w);
        #pragma unroll
        for (int off = 32; off > 0; off >>= 1)
            ts += __shfl_down(ts, off, 64);
        if (lane == 0) sred[8 + wid] = ts;  // slots 8..15
    }
    __syncthreads();
    float S = 0.0f;
    #pragma unroll
    for (int i = 8; i < 16; ++i) S += sred[i];

    if (t < COLS4) {
        const float inv = 1.0f / S;
        float4 gg;
        gg.x = e.x * inv; gg.y = e.y * inv; gg.z = e.z * inv; gg.w = e.w * inv;
        pm[0][t] = gg;                   // gate broadcast buffer
    }
    __syncthreads();

    const float4 g = pm[0][col];

    // ---- Pass 2: out = gate * x (same rotation) ----
    #pragma unroll 8
    for (int c = 0; c < 32; ++c) {
        const int cc = c0 + ((c + b) & 31);
        const size_t idx = (size_t)cc * COLS4 + col;
        float4 v = xb[idx];
        float4 o;
        o.x = v.x * g.x;
        o.y = v.y * g.y;
        o.z = v.z * g.z;
        o.w = v.w * g.w;
        ob[idx] = o;
    }
}

extern "C" void kernel_launch(void* const* d_in, const int* in_sizes, int n_in,
                              void* d_out, int out_size, void* d_ws, size_t ws_size,
                              hipStream_t stream) {
    const float* x = (const float*)d_in[0];
    float* out = (float*)d_out;
    ssa_gate_kernel<<<B_DIM, THREADS, 0, stream>>>(x, out);
}